// Round 4
// baseline (941.419 us; speedup 1.0000x reference)
//
#include <hip/hip_runtime.h>
#include <hip/hip_bf16.h>
#include <stdint.h>
#include <stddef.h>

typedef __bf16 bf16;
typedef __bf16 bf16x4 __attribute__((ext_vector_type(4)));
typedef __bf16 bf16x8 __attribute__((ext_vector_type(8)));
typedef float  f32x4  __attribute__((ext_vector_type(4)));

__device__ __forceinline__ void async16(const void* src, void* dst) {
    __builtin_amdgcn_global_load_lds(
        (__attribute__((address_space(1))) void*)(void*)(src),
        (__attribute__((address_space(3))) void*)(dst),
        16, 0, 0);
}

#define MEMFENCE asm volatile("" ::: "memory")

__device__ __forceinline__ void barrier_f() {
    MEMFENCE;
    __builtin_amdgcn_s_barrier();
    MEMFENCE;
}

// ---------------------------------------------------------------------------
// Kernel 0: f32 -> bf16 weight conversion (n divisible by 4)
// ---------------------------------------------------------------------------
__global__ __launch_bounds__(256)
void f2b(const float* __restrict__ src, bf16* __restrict__ dst, int n)
{
    const int i = (blockIdx.x * 256 + threadIdx.x) * 4;
    if (i < n) {
        f32x4 c = *(const f32x4*)(src + i);
        bf16x4 o;
        #pragma unroll
        for (int q = 0; q < 4; ++q) o[q] = (bf16)c[q];
        *(bf16x4*)(dst + i) = o;
    }
}

// ---------------------------------------------------------------------------
// Kernel 1: LN over x rows (768, f32 in) + window permutation -> bf16 Y.
// ---------------------------------------------------------------------------
__global__ __launch_bounds__(256)
void ln1_win(const float* __restrict__ x, const float* __restrict__ g,
             const float* __restrict__ b, bf16* __restrict__ Y)
{
    const int row  = blockIdx.x * 4 + (threadIdx.x >> 6);
    const int lane = threadIdx.x & 63;
    const float* xr = x + (size_t)row * 768;
    float v[12];
    float sum = 0.f, ssq = 0.f;
    #pragma unroll
    for (int j = 0; j < 3; ++j) {
        f32x4 c = *(const f32x4*)(xr + j * 256 + lane * 4);
        #pragma unroll
        for (int q = 0; q < 4; ++q) {
            float f = c[q];
            v[j * 4 + q] = f; sum += f; ssq += f * f;
        }
    }
    #pragma unroll
    for (int d = 1; d < 64; d <<= 1) {
        sum += __shfl_xor(sum, d, 64);
        ssq += __shfl_xor(ssq, d, 64);
    }
    const float mean = sum * (1.f / 768.f);
    const float rstd = rsqrtf(ssq * (1.f / 768.f) - mean * mean + 1e-5f);
    const int bb = row >> 14;
    const int l  = row & 16383;
    const int hy = l >> 7, wx = l & 127;
    const int m  = ((bb * 256 + (hy >> 3) * 16 + (wx >> 3)) << 6)
                 + ((hy & 7) << 3) + (wx & 7);
    bf16* yr = Y + (size_t)m * 768;
    #pragma unroll
    for (int j = 0; j < 3; ++j) {
        const int c0 = j * 256 + lane * 4;
        f32x4 gg = *(const f32x4*)(g + c0);
        f32x4 bv = *(const f32x4*)(b + c0);
        bf16x4 ov;
        #pragma unroll
        for (int q = 0; q < 4; ++q)
            ov[q] = (bf16)((v[j * 4 + q] - mean) * rstd * gg[q] + bv[q]);
        *(bf16x4*)(yr + c0) = ov;
    }
}

// ---------------------------------------------------------------------------
// Kernel 1b: Gbuf[f] = Y[Smod+f] + Y[2*Smod+f]  (green+blue), f < Smod.
// ---------------------------------------------------------------------------
__global__ __launch_bounds__(256)
void gsum(const bf16* __restrict__ Y, bf16* __restrict__ G, int Smod)
{
    const int i = (blockIdx.x * 256 + threadIdx.x) * 8;
    if (i < Smod) {
        bf16x8 a = *(const bf16x8*)(Y + Smod + i);
        bf16x8 c = *(const bf16x8*)(Y + 2 * Smod + i);
        bf16x8 r;
        #pragma unroll
        for (int q = 0; q < 8; ++q) r[q] = (bf16)((float)a[q] + (float)c[q]);
        *(bf16x8*)(G + i) = r;
    }
}

// ---------------------------------------------------------------------------
// GEMM, B-direct variant. C = A @ B^T (+bias).
// BM=256, BN=256, BK=64, 512 threads = 8 waves (2M x 4N), per-wave 128x64.
//
// Key change vs r3: B (weights, L2-resident) is loaded DIRECTLY global->VGPR
// (per-lane contiguous 16B = dwordx4), half-K-tile prefetched. Only A goes
// through LDS: 3 buffers x A[2ks][256][32] = 96 KB, staged 2 tiles ahead via
// global_load_lds (pre-swizzled source, linear dest). LDS traffic per
// block-K-tile drops 256KB -> 160KB; one barrier per K-tile (12 total).
//
// Sync ledger (no manual in-loop vmcnt): per wave, issue order per kt is
//   [stage A(kt+2): 4 vm] < [load Bb(kt,ks1): 4 vm] < [load Ba(kt+1,ks0): 4 vm]
// The compiler's own vmcnt before mma-uses of Ba/Bb (FIFO retire) therefore
// retires stage(kt+1)/(kt+2) BEFORE the end-of-kt barrier; the barrier then
// publishes buf[kt+1] to all waves. sched_barrier(0) pins the mma+waits
// pre-barrier. WAR: stage target buf[(kt+2)%3] last read at kt-1, separated
// by the kt-1 end barrier. Prologue: manual vmcnt(4) retires stage(0)+Ba(0).
//
// Swizzle (unchanged): halves [256][32], chunk c of row r holds source col
// c ^ ((r>>1)&3) -> 2-way bank aliasing (free) on ds_read_b128.
// XCD swizzle: bid&7 = XCD, contiguous m-chunk per XCD, nbase fastest.
// AMODE 1: A gathered from (nbase<768 ? Gbuf : Y) at (m*768+k) mod Smod.
// ---------------------------------------------------------------------------
template<int AMODE, bool BIAS>
__global__ __launch_bounds__(512, 2)
void gemm_bd(const bf16* __restrict__ A, const bf16* __restrict__ Yg,
             const bf16* __restrict__ Gb, const bf16* __restrict__ Bm,
             const float* __restrict__ bias, bf16* __restrict__ Cm,
             int K, int ldc, int Smod, int nb_n)
{
    __shared__ bf16 lds[3 * 16384];            // 96 KB, A only

    const int per    = gridDim.x >> 3;
    const int mchunk = per / nb_n;
    const int xcd    = blockIdx.x & 7;
    const int slot_b = blockIdx.x >> 3;
    const int mbase  = (xcd * mchunk + slot_b / nb_n) * 256;
    const int nbase  = (slot_b % nb_n) * 256;

    const int tid  = threadIdx.x;
    const int lane = tid & 63;
    const int w    = tid >> 6;
    const int quad = lane >> 4;
    const int l16  = lane & 15;
    const int wm   = (w >> 2) * 128;           // 2 M-waves
    const int wn   = (w & 3) * 64;             // 4 N-waves

    const bf16* Asrc = (AMODE == 1) ? ((nbase < 768) ? Gb : Yg) : A;
    const int nt = K >> 6;

    // ---- A staging constants: thread covers rows r0, r0+128; chunk cq ----
    const int r0 = tid >> 2;
    const int cq = tid & 3;
    const int q0 = cq ^ ((r0 >> 1) & 3);       // == value for r0+128 too
    int fA0 = 0, fA1 = 0;
    const bf16 *aP0 = nullptr, *aP1 = nullptr;
    if (AMODE == 1) {
        fA0 = (mbase + r0) * 768 + q0 * 8;
        if (fA0 >= 2 * Smod) fA0 -= 2 * Smod;
        else if (fA0 >= Smod) fA0 -= Smod;
        fA1 = (mbase + r0 + 128) * 768 + q0 * 8;
        if (fA1 >= 2 * Smod) fA1 -= 2 * Smod;
        else if (fA1 >= Smod) fA1 -= Smod;
    } else {
        aP0 = A + (size_t)(mbase + r0) * K + q0 * 8;
        aP1 = A + (size_t)(mbase + r0 + 128) * K + q0 * 8;
    }
    const int ldst0 = tid * 8;                  // elem offset in half
    const int ldst1 = tid * 8 + 4096;

    // stage full A K-tile (2 halves, 4 async16) into buf[kt%3]
    auto stageA = [&](int kt) {
        bf16* dst = lds + (kt % 3) * 16384;
        const int kb = kt * 64;
        #pragma unroll
        for (int ks = 0; ks < 2; ++ks) {
            const int ko = kb + ks * 32;
            const bf16 *s0, *s1;
            if (AMODE == 1) {
                int f = fA0 + ko; if (f >= Smod) f -= Smod;
                int g = fA1 + ko; if (g >= Smod) g -= Smod;
                s0 = Asrc + f; s1 = Asrc + g;
            } else {
                s0 = aP0 + ko; s1 = aP1 + ko;
            }
            async16(s0, dst + ks * 8192 + ldst0);
            async16(s1, dst + ks * 8192 + ldst1);
        }
    };

    // ---- per-thread LDS read offsets (elements, within a half) ----
    int aoff[8];
    #pragma unroll
    for (int i = 0; i < 8; ++i) {
        const int r = wm + 16 * i + l16;
        aoff[i] = r * 32 + (quad ^ ((r >> 1) & 3)) * 8;
    }

    // ---- B row pointers: 4 fragments (b = nh*2+jj -> col wn+16*b) ----
    const bf16* bPtr[4];
    #pragma unroll
    for (int b = 0; b < 4; ++b) {
        const int row = nbase + wn + 16 * b + l16;
        bPtr[b] = Bm + (size_t)row * K + quad * 8;
    }

    bf16x8 af[8], Ba[4], Bb[4];
    auto readA = [&](int kt, int ks) {
        const bf16* base = lds + (kt % 3) * 16384 + ks * 8192;
        #pragma unroll
        for (int i = 0; i < 8; ++i) af[i] = *(const bf16x8*)(base + aoff[i]);
    };

    const f32x4 zero = {0.f, 0.f, 0.f, 0.f};
    f32x4 acc[8][4];
    #pragma unroll
    for (int i = 0; i < 8; ++i)
        #pragma unroll
        for (int j = 0; j < 4; ++j) acc[i][j] = zero;

    auto mma32 = [&](const bf16x8* bb) {
        __builtin_amdgcn_s_setprio(1);
        #pragma unroll
        for (int i = 0; i < 8; ++i)
            #pragma unroll
            for (int b = 0; b < 4; ++b)
                acc[i][b] = __builtin_amdgcn_mfma_f32_16x16x32_bf16(
                    af[i], bb[b], acc[i][b], 0, 0, 0);
        __builtin_amdgcn_s_setprio(0);
    };

    // ---- prologue: stage(0) < Ba(0,ks0) < stage(1); retire first 8 ----
    stageA(0);
    MEMFENCE;
    #pragma unroll
    for (int b = 0; b < 4; ++b) Ba[b] = *(const bf16x8*)(bPtr[b]);
    MEMFENCE;
    if (nt > 1) stageA(1);
    MEMFENCE;
    asm volatile("s_waitcnt vmcnt(4)" ::: "memory");
    barrier_f();

    for (int kt = 0; kt < nt; ++kt) {
        const int koff = kt * 64;

        readA(kt, 0);                          // 8 ds_read_b128
        if (kt + 2 < nt) stageA(kt + 2);       // 4 async16
        MEMFENCE;
        #pragma unroll
        for (int b = 0; b < 4; ++b)            // Bb = B(kt, ks1)
            Bb[b] = *(const bf16x8*)(bPtr[b] + koff + 32);
        MEMFENCE;

        mma32(Ba);                             // ks0 (32 MFMA)

        readA(kt, 1);                          // 8 ds_read_b128
        if (kt + 1 < nt) {
            #pragma unroll
            for (int b = 0; b < 4; ++b)        // Ba = B(kt+1, ks0)
                Ba[b] = *(const bf16x8*)(bPtr[b] + koff + 64);
        }
        MEMFENCE;

        mma32(Bb);                             // ks1 (32 MFMA)

        __builtin_amdgcn_sched_barrier(0);     // pin mma+waits pre-barrier
        barrier_f();
    }

    // epilogue: C/D layout col=lane&15, row=quad*4+reg
    #pragma unroll
    for (int i = 0; i < 8; ++i) {
        const int row0 = mbase + wm + 16 * i + quad * 4;
        #pragma unroll
        for (int j = 0; j < 4; ++j) {
            const int col = nbase + wn + 16 * j + l16;
            float bv = 0.f;
            if (BIAS) bv = bias[col];
            #pragma unroll
            for (int r = 0; r < 4; ++r)
                Cm[(size_t)(row0 + r) * ldc + col] = (bf16)(acc[i][j][r] + bv);
        }
    }
}

// ---------------------------------------------------------------------------
// Kernel 3: windowed attention, one wave per (window, head). 64x64 tiles.
// ---------------------------------------------------------------------------
__global__ __launch_bounds__(64)
void attn_win(const bf16* __restrict__ QKV, bf16* __restrict__ AOut)
{
    const int blk  = blockIdx.x;
    const int bw   = blk / 12;
    const int h    = blk % 12;
    const int lane = threadIdx.x;
    const int quad = lane >> 4;
    const int l16  = lane & 15;

    __shared__ bf16 Kt[64 * 64];
    __shared__ bf16 Vt[64 * 64];

    const size_t rowbase = (size_t)bw * 64;

    {
        const int rsub = lane >> 3;
        const int slot = lane & 7;
        #pragma unroll
        for (int t = 0; t < 8; ++t) {
            const int row = 8 * t + rsub;
            const int kcK = slot ^ (row & 7);
            async16(QKV + (rowbase + row) * 2304 + 768 + h * 64 + kcK * 8,
                    Kt + (8 * t) * 64);
            async16(QKV + (rowbase + row) * 2304 + 1536 + h * 64 + slot * 8,
                    Vt + (8 * t) * 64);
        }
    }

    bf16x8 qf[4][2];
    #pragma unroll
    for (int i = 0; i < 4; ++i)
        #pragma unroll
        for (int ks = 0; ks < 2; ++ks)
            qf[i][ks] = *(const bf16x8*)(QKV + (rowbase + 16 * i + l16) * 2304
                                         + h * 64 + ks * 32 + quad * 8);
    __syncthreads();

    const f32x4 zero = {0.f, 0.f, 0.f, 0.f};
    f32x4 s[4][4];
    #pragma unroll
    for (int i = 0; i < 4; ++i)
        #pragma unroll
        for (int j = 0; j < 4; ++j) s[i][j] = zero;

    #pragma unroll
    for (int ks = 0; ks < 2; ++ks) {
        bf16x8 kf[4];
        #pragma unroll
        for (int j = 0; j < 4; ++j) {
            const int row  = 16 * j + l16;
            const int slot = (ks * 4 + quad) ^ (row & 7);
            kf[j] = *(const bf16x8*)(Kt + row * 64 + slot * 8);
        }
        #pragma unroll
        for (int i = 0; i < 4; ++i)
            #pragma unroll
            for (int j = 0; j < 4; ++j)
                s[i][j] = __builtin_amdgcn_mfma_f32_16x16x32_bf16(
                    qf[i][ks], kf[j], s[i][j], 0, 0, 0);
    }

    float rrec[4][4];
    #pragma unroll
    for (int i = 0; i < 4; ++i) {
        #pragma unroll
        for (int r = 0; r < 4; ++r) {
            float mx = s[i][0][r];
            #pragma unroll
            for (int j = 1; j < 4; ++j) mx = fmaxf(mx, s[i][j][r]);
            #pragma unroll
            for (int d = 1; d < 16; d <<= 1) mx = fmaxf(mx, __shfl_xor(mx, d, 64));
            float sum = 0.f;
            #pragma unroll
            for (int j = 0; j < 4; ++j) {
                float p = __expf((s[i][j][r] - mx) * 0.125f);
                s[i][j][r] = p;
                sum += p;
            }
            #pragma unroll
            for (int d = 1; d < 16; d <<= 1) sum += __shfl_xor(sum, d, 64);
            rrec[i][r] = 1.f / sum;
        }
    }

    #pragma unroll
    for (int i = 0; i < 4; ++i)
        #pragma unroll
        for (int j = 0; j < 4; ++j)
            #pragma unroll
            for (int r = 0; r < 4; ++r) {
                const int row  = 16 * i + quad * 4 + r;
                const int col  = 16 * j + l16;
                const int slot = (col >> 3) ^ (row & 7);
                Kt[row * 64 + slot * 8 + (col & 7)] = (bf16)s[i][j][r];
            }
    __syncthreads();

    f32x4 o[4][4];
    #pragma unroll
    for (int i = 0; i < 4; ++i)
        #pragma unroll
        for (int j = 0; j < 4; ++j) o[i][j] = zero;

    #pragma unroll
    for (int ks = 0; ks < 2; ++ks) {
        bf16x8 pf[4], vf[4];
        #pragma unroll
        for (int i = 0; i < 4; ++i) {
            const int row  = 16 * i + l16;
            const int slot = (ks * 4 + quad) ^ (row & 7);
            pf[i] = *(const bf16x8*)(Kt + row * 64 + slot * 8);
        }
        #pragma unroll
        for (int j = 0; j < 4; ++j) {
            bf16x8 t;
            #pragma unroll
            for (int q = 0; q < 8; ++q)
                t[q] = Vt[(ks * 32 + quad * 8 + q) * 64 + 16 * j + l16];
            vf[j] = t;
        }
        #pragma unroll
        for (int i = 0; i < 4; ++i)
            #pragma unroll
            for (int j = 0; j < 4; ++j)
                o[i][j] = __builtin_amdgcn_mfma_f32_16x16x32_bf16(
                    pf[i], vf[j], o[i][j], 0, 0, 0);
    }

    #pragma unroll
    for (int i = 0; i < 4; ++i)
        #pragma unroll
        for (int j = 0; j < 4; ++j)
            #pragma unroll
            for (int r = 0; r < 4; ++r) {
                const size_t grow = rowbase + 16 * i + quad * 4 + r;
                const int col = h * 64 + 16 * j + l16;
                AOut[grow * 768 + col] = (bf16)(o[i][j][r] * rrec[i][r]);
            }
}

// ---------------------------------------------------------------------------
// Kernel 5: LN2 + fc1 (C->1) + exact gelu + fc2 (1->C). 1 wave per row.
// ---------------------------------------------------------------------------
__global__ __launch_bounds__(256)
void final_fused(const bf16* __restrict__ P, const float* __restrict__ g2,
                 const float* __restrict__ b2, const float* __restrict__ fc1w,
                 const float* __restrict__ fc1b, const float* __restrict__ fc2w,
                 const float* __restrict__ fc2b, float* __restrict__ out)
{
    const int row  = blockIdx.x * 4 + (threadIdx.x >> 6);
    const int lane = threadIdx.x & 63;
    const bf16* pr = P + (size_t)row * 768;
    float v[12];
    float sum = 0.f, ssq = 0.f;
    #pragma unroll
    for (int j = 0; j < 3; ++j) {
        bf16x4 c = *(const bf16x4*)(pr + j * 256 + lane * 4);
        #pragma unroll
        for (int q = 0; q < 4; ++q) {
            float f = (float)c[q];
            v[j * 4 + q] = f; sum += f; ssq += f * f;
        }
    }
    #pragma unroll
    for (int d = 1; d < 64; d <<= 1) {
        sum += __shfl_xor(sum, d, 64);
        ssq += __shfl_xor(ssq, d, 64);
    }
    const float mean = sum * (1.f / 768.f);
    const float rstd = rsqrtf(ssq * (1.f / 768.f) - mean * mean + 1e-5f);
    float part = 0.f;
    #pragma unroll
    for (int j = 0; j < 3; ++j) {
        const int c0 = j * 256 + lane * 4;
        f32x4 gg = *(const f32x4*)(g2 + c0);
        f32x4 bb = *(const f32x4*)(b2 + c0);
        f32x4 f1 = *(const f32x4*)(fc1w + c0);
        #pragma unroll
        for (int q = 0; q < 4; ++q) {
            float ln = (v[j * 4 + q] - mean) * rstd * gg[q] + bb[q];
            part += ln * f1[q];
        }
    }
    #pragma unroll
    for (int d = 1; d < 64; d <<= 1) part += __shfl_xor(part, d, 64);
    const float sv = part + fc1b[0];
    const float ge = 0.5f * sv * (1.f + erff(sv * 0.70710678118654752f));
    float* orow = out + (size_t)row * 768;
    #pragma unroll
    for (int j = 0; j < 3; ++j) {
        const int c0 = j * 256 + lane * 4;
        f32x4 f2  = *(const f32x4*)(fc2w + c0);
        f32x4 b2v = *(const f32x4*)(fc2b + c0);
        f32x4 ov;
        #pragma unroll
        for (int q = 0; q < 4; ++q)
            ov[q] = ge * f2[q] + b2v[q];
        *(f32x4*)(orow + c0) = ov;
    }
}

// ---------------------------------------------------------------------------
extern "C" void kernel_launch(void* const* d_in, const int* in_sizes, int n_in,
                              void* d_out, int out_size, void* d_ws, size_t ws_size,
                              hipStream_t stream)
{
    const float* x     = (const float*)d_in[0];
    const float* n1g   = (const float*)d_in[1];
    const float* n1b   = (const float*)d_in[2];
    const float* n2g   = (const float*)d_in[3];
    const float* n2b   = (const float*)d_in[4];
    const float* qkvw  = (const float*)d_in[5];
    const float* projw = (const float*)d_in[6];
    const float* projb = (const float*)d_in[7];
    const float* fc1w  = (const float*)d_in[8];
    const float* fc1b  = (const float*)d_in[9];
    const float* fc2w  = (const float*)d_in[10];
    const float* fc2b  = (const float*)d_in[11];
    float* out = (float*)d_out;

    const int total = in_sizes[0];          // B * 16384 * 768
    const int rows  = total / 768;          // 65536 token rows
    const int Smod  = total / 3;            // 2^24 for B=4
    const int Bw    = rows / 64;            // windows
    const int C     = 768;

    bf16* qkv     = (bf16*)d_ws;
    bf16* Ybuf    = qkv + (size_t)rows * 2304;
    bf16* qkvw_b  = Ybuf + (size_t)rows * 768;
    bf16* projw_b = qkvw_b + (size_t)3 * C * C;
    bf16* Pbuf    = qkv;
    // Gbuf lives in d_out scratch (33.5MB << out_size; final_fused fully
    // overwrites out afterwards).
    bf16* Gb      = (bf16*)d_out;

    const int nqkvw  = 3 * C * C;
    const int nprojw = C * C;
    f2b<<<(nqkvw / 4 + 255) / 256, 256, 0, stream>>>(qkvw, qkvw_b, nqkvw);
    f2b<<<(nprojw / 4 + 255) / 256, 256, 0, stream>>>(projw, projw_b, nprojw);

    ln1_win<<<rows / 4, 256, 0, stream>>>(x, n1g, n1b, Ybuf);

    gsum<<<(Smod / 8 + 255) / 256, 256, 0, stream>>>(Ybuf, Gb, Smod);

    const int nbm = rows / 256;             // 256 m-tiles
    gemm_bd<1, false><<<nbm * 9, 512, 0, stream>>>(
        nullptr, Ybuf, Gb, qkvw_b, nullptr, qkv, 768, 2304, Smod, 9);

    attn_win<<<Bw * 12, 64, 0, stream>>>(qkv, Ybuf);

    gemm_bd<0, true><<<nbm * 3, 512, 0, stream>>>(
        Ybuf, nullptr, nullptr, projw_b, projb, Pbuf, 768, 768, 0, 3);

    final_fused<<<rows / 4, 256, 0, stream>>>(Pbuf, n2g, n2b, fc1w, fc1b,
                                              fc2w, fc2b, out);
}

// Round 5
// 867.361 us; speedup vs baseline: 1.0854x; 1.0854x over previous
//
#include <hip/hip_runtime.h>
#include <hip/hip_bf16.h>
#include <stdint.h>
#include <stddef.h>

typedef __bf16 bf16;
typedef __bf16 bf16x4 __attribute__((ext_vector_type(4)));
typedef __bf16 bf16x8 __attribute__((ext_vector_type(8)));
typedef float  f32x4  __attribute__((ext_vector_type(4)));
typedef float  f32x16 __attribute__((ext_vector_type(16)));

__device__ __forceinline__ void async16(const void* src, void* dst) {
    __builtin_amdgcn_global_load_lds(
        (__attribute__((address_space(1))) void*)(void*)(src),
        (__attribute__((address_space(3))) void*)(dst),
        16, 0, 0);
}

#define MEMFENCE asm volatile("" ::: "memory")

__device__ __forceinline__ void barrier_f() {
    MEMFENCE;
    __builtin_amdgcn_s_barrier();
    MEMFENCE;
}

// ---------------------------------------------------------------------------
// Kernel 0: f32 -> bf16 weight conversion (n divisible by 4)
// ---------------------------------------------------------------------------
__global__ __launch_bounds__(256)
void f2b(const float* __restrict__ src, bf16* __restrict__ dst, int n)
{
    const int i = (blockIdx.x * 256 + threadIdx.x) * 4;
    if (i < n) {
        f32x4 c = *(const f32x4*)(src + i);
        bf16x4 o;
        #pragma unroll
        for (int q = 0; q < 4; ++q) o[q] = (bf16)c[q];
        *(bf16x4*)(dst + i) = o;
    }
}

// ---------------------------------------------------------------------------
// Kernel 1: LN over x rows (768, f32 in) + window permutation -> bf16 Y.
// ---------------------------------------------------------------------------
__global__ __launch_bounds__(256)
void ln1_win(const float* __restrict__ x, const float* __restrict__ g,
             const float* __restrict__ b, bf16* __restrict__ Y)
{
    const int row  = blockIdx.x * 4 + (threadIdx.x >> 6);
    const int lane = threadIdx.x & 63;
    const float* xr = x + (size_t)row * 768;
    float v[12];
    float sum = 0.f, ssq = 0.f;
    #pragma unroll
    for (int j = 0; j < 3; ++j) {
        f32x4 c = *(const f32x4*)(xr + j * 256 + lane * 4);
        #pragma unroll
        for (int q = 0; q < 4; ++q) {
            float f = c[q];
            v[j * 4 + q] = f; sum += f; ssq += f * f;
        }
    }
    #pragma unroll
    for (int d = 1; d < 64; d <<= 1) {
        sum += __shfl_xor(sum, d, 64);
        ssq += __shfl_xor(ssq, d, 64);
    }
    const float mean = sum * (1.f / 768.f);
    const float rstd = rsqrtf(ssq * (1.f / 768.f) - mean * mean + 1e-5f);
    const int bb = row >> 14;
    const int l  = row & 16383;
    const int hy = l >> 7, wx = l & 127;
    const int m  = ((bb * 256 + (hy >> 3) * 16 + (wx >> 3)) << 6)
                 + ((hy & 7) << 3) + (wx & 7);
    bf16* yr = Y + (size_t)m * 768;
    #pragma unroll
    for (int j = 0; j < 3; ++j) {
        const int c0 = j * 256 + lane * 4;
        f32x4 gg = *(const f32x4*)(g + c0);
        f32x4 bv = *(const f32x4*)(b + c0);
        bf16x4 ov;
        #pragma unroll
        for (int q = 0; q < 4; ++q)
            ov[q] = (bf16)((v[j * 4 + q] - mean) * rstd * gg[q] + bv[q]);
        *(bf16x4*)(yr + c0) = ov;
    }
}

// ---------------------------------------------------------------------------
// Kernel 1b: Gbuf[f] = Y[Smod+f] + Y[2*Smod+f]  (green+blue), f < Smod.
// ---------------------------------------------------------------------------
__global__ __launch_bounds__(256)
void gsum(const bf16* __restrict__ Y, bf16* __restrict__ G, int Smod)
{
    const int i = (blockIdx.x * 256 + threadIdx.x) * 8;
    if (i < Smod) {
        bf16x8 a = *(const bf16x8*)(Y + Smod + i);
        bf16x8 c = *(const bf16x8*)(Y + 2 * Smod + i);
        bf16x8 r;
        #pragma unroll
        for (int q = 0; q < 8; ++q) r[q] = (bf16)((float)a[q] + (float)c[q]);
        *(bf16x8*)(G + i) = r;
    }
}

// ---------------------------------------------------------------------------
// GEMM, r3 single-barrier 4-phase schedule + 32x32x16 MFMA.
// C = A @ B^T (+bias). BM=256, BN=256, BK=64, 512 threads = 8 waves
// (2M x 4N), per-wave 128x64 = 4 m-frags x 2 n-frags of 32x32.
// LDS = 2 dbuf x { A[2ks][256][32] | B[2ks][256][32] } = 128 KB (identical
// to r3; staging, swizzle, vmcnt ledger byte-for-byte the same).
//
// 32x32x16 fragment maps:
//   A/B operand: row = lane&31, k-elems = (lane>>5)*8..+7 (8 contiguous).
//     Within a 32-k LDS half, k16-step kk needs source chunk kk*2+(lane>>5).
//   C/D: col = lane&31, row = (reg&3) + 8*(reg>>2) + 4*(lane>>5). [m74/m101]
// MFMA count per K-tile per wave: 4m x 2n x 4 k16 = 32 (vs 64 of 16x16x32)
// at ~8cyc each -> ~15% fewer matrix-pipe cycles (m119: 2495 vs 2176 TF).
//
// Phase = { s_barrier ; 8 MFMA (frags read LAST phase) ; ds_reads for NEXT
// phase ; [stage 4 gload_lds] ; [counted vmcnt(8)] }.  Ledger as r3:
// P1 stages (kt+1).K1, P3 stages (kt+2).K0; steady in-flight 8..12;
// vmcnt(8) retires exactly the half-tile needed one phase later.
// ---------------------------------------------------------------------------
template<int AMODE, bool BIAS>
__global__ __launch_bounds__(512, 2)
void gemm32(const bf16* __restrict__ A, const bf16* __restrict__ Yg,
            const bf16* __restrict__ Gb, const bf16* __restrict__ Bm,
            const float* __restrict__ bias, bf16* __restrict__ Cm,
            int K, int ldc, int Smod, int nb_n)
{
    __shared__ bf16 lds[2 * 32768];            // 128 KB

    const int per    = gridDim.x >> 3;
    const int mchunk = per / nb_n;
    const int xcd    = blockIdx.x & 7;
    const int slot_b = blockIdx.x >> 3;
    const int mbase  = (xcd * mchunk + slot_b / nb_n) * 256;
    const int nbase  = (slot_b % nb_n) * 256;

    const int tid  = threadIdx.x;
    const int lane = tid & 63;
    const int w    = tid >> 6;
    const int l31  = lane & 31;
    const int k8   = lane >> 5;                // k-chunk selector
    const int wm   = (w >> 2) * 128;           // 2 M-waves
    const int wn   = (w & 3) * 64;             // 4 N-waves

    const bf16* Asrc = (AMODE == 1) ? ((nbase < 768) ? Gb : Yg) : A;
    const int nt = K >> 6;

    // ---- staging constants (identical to r3) ----
    const int r0 = tid >> 2, r1 = r0 + 128;
    const int sq0 = (tid & 3) ^ ((r0 >> 1) & 3);
    const int sq1 = (tid & 3) ^ ((r1 >> 1) & 3);
    const int lo0 = tid * 8, lo1 = tid * 8 + 4096;

    int f0A0 = 0, f0A1 = 0;
    const bf16 *aP0 = nullptr, *aP1 = nullptr;
    if (AMODE == 1) {
        f0A0 = (mbase + r0) * 768 + sq0 * 8;
        if (f0A0 >= 2 * Smod) f0A0 -= 2 * Smod;
        else if (f0A0 >= Smod) f0A0 -= Smod;
        f0A1 = (mbase + r1) * 768 + sq1 * 8;
        if (f0A1 >= 2 * Smod) f0A1 -= 2 * Smod;
        else if (f0A1 >= Smod) f0A1 -= Smod;
    } else {
        aP0 = A + (size_t)(mbase + r0) * K + sq0 * 8;
        aP1 = A + (size_t)(mbase + r1) * K + sq1 * 8;
    }
    const bf16* bP0 = Bm + (size_t)(nbase + r0) * K + sq0 * 8;
    const bf16* bP1 = Bm + (size_t)(nbase + r1) * K + sq1 * 8;

    // stage one full K-half (A 256x32 + B 256x32, 4 loads) of tile kt
    auto stageK = [&](int kt, int ks) {
        const int kb = kt * 64 + ks * 32;
        bf16* dst = lds + (kt & 1) * 32768 + ks * 8192;
        const bf16 *s0, *s1;
        if (AMODE == 1) {
            int f = f0A0 + kb; if (f >= Smod) f -= Smod;
            int g = f0A1 + kb; if (g >= Smod) g -= Smod;
            s0 = Asrc + f; s1 = Asrc + g;
        } else {
            s0 = aP0 + kb; s1 = aP1 + kb;
        }
        async16(s0, dst + lo0);
        async16(s1, dst + lo1);
        async16(bP0 + kb, dst + 16384 + lo0);
        async16(bP1 + kb, dst + 16384 + lo1);
    };

    // ---- per-thread LDS read offsets (elements) ----
    int aoff[2][4], boff[2][2];                // [kk][frag]
    #pragma unroll
    for (int kk = 0; kk < 2; ++kk) {
        #pragma unroll
        for (int i = 0; i < 4; ++i) {
            const int r = wm + 32 * i + l31;
            aoff[kk][i] = r * 32 + ((kk * 2 + k8) ^ ((r >> 1) & 3)) * 8;
        }
        #pragma unroll
        for (int j = 0; j < 2; ++j) {
            const int r = wn + 32 * j + l31;
            boff[kk][j] = r * 32 + ((kk * 2 + k8) ^ ((r >> 1) & 3)) * 8;
        }
    }

    bf16x8 af[2][4], b0[2], b1[2];
    auto readA = [&](int p, int ks) {
        const bf16* base = lds + p + ks * 8192;
        #pragma unroll
        for (int kk = 0; kk < 2; ++kk)
            #pragma unroll
            for (int i = 0; i < 4; ++i)
                af[kk][i] = *(const bf16x8*)(base + aoff[kk][i]);
    };
    auto readB0 = [&](int p, int ks, int j) {
        const bf16* base = lds + p + 16384 + ks * 8192;
        #pragma unroll
        for (int kk = 0; kk < 2; ++kk)
            b0[kk] = *(const bf16x8*)(base + boff[kk][j]);
    };
    auto readB1 = [&](int p, int ks, int j) {
        const bf16* base = lds + p + 16384 + ks * 8192;
        #pragma unroll
        for (int kk = 0; kk < 2; ++kk)
            b1[kk] = *(const bf16x8*)(base + boff[kk][j]);
    };

    f32x16 acc[4][2];
    #pragma unroll
    for (int i = 0; i < 4; ++i)
        #pragma unroll
        for (int j = 0; j < 2; ++j)
            #pragma unroll
            for (int r = 0; r < 16; ++r) acc[i][j][r] = 0.f;

    auto mma8 = [&](const bf16x8* bb, int j) {
        __builtin_amdgcn_s_setprio(1);
        #pragma unroll
        for (int kk = 0; kk < 2; ++kk)
            #pragma unroll
            for (int i = 0; i < 4; ++i)
                acc[i][j] = __builtin_amdgcn_mfma_f32_32x32x16_bf16(
                    af[kk][i], bb[kk], acc[i][j], 0, 0, 0);
        __builtin_amdgcn_s_setprio(0);
    };

    // ---- prologue: stage (0).K0, (0).K1, (1).K0; wait (0).K0; preload P1 ----
    stageK(0, 0); stageK(0, 1);
    if (nt > 1) {
        stageK(1, 0);
        asm volatile("s_waitcnt vmcnt(8)" ::: "memory");
    } else {
        asm volatile("s_waitcnt vmcnt(4)" ::: "memory");
    }
    barrier_f();
    readA(0, 0);
    readB0(0, 0, 0);

    for (int kt = 0; kt < nt; ++kt) {
        const int p = (kt & 1) * 32768;

        // ---- P1: MFMA(ks0, j0) ----
        barrier_f();
        mma8(b0, 0);
        readB1(p, 0, 1);                       // for P2
        if (kt + 1 < nt) {
            stageK(kt + 1, 1);
            asm volatile("s_waitcnt vmcnt(8)" ::: "memory");
        } else {
            asm volatile("s_waitcnt vmcnt(0)" ::: "memory");
        }

        // ---- P2: MFMA(ks0, j1) ----
        barrier_f();
        mma8(b1, 1);
        readA(p, 1);                           // for P3 (overwrites af)
        readB0(p, 1, 0);                       // for P3

        // ---- P3: MFMA(ks1, j0) ----
        barrier_f();
        mma8(b0, 0);
        readB1(p, 1, 1);                       // for P4
        if (kt + 2 < nt) {
            stageK(kt + 2, 0);
            asm volatile("s_waitcnt vmcnt(8)" ::: "memory");
        } else if (kt + 1 < nt) {
            asm volatile("s_waitcnt vmcnt(4)" ::: "memory");
        } else {
            asm volatile("s_waitcnt vmcnt(0)" ::: "memory");
        }

        // ---- P4: MFMA(ks1, j1) ----
        barrier_f();
        mma8(b1, 1);
        if (kt + 1 < nt) {
            const int pn = ((kt + 1) & 1) * 32768;
            readA(pn, 0);                      // for P1(kt+1)
            readB0(pn, 0, 0);
        }
    }

    // epilogue: 32x32 C/D layout: col=lane&31, row=(r&3)+8*(r>>2)+4*k8
    #pragma unroll
    for (int i = 0; i < 4; ++i) {
        const int rowb = mbase + wm + 32 * i + 4 * k8;
        #pragma unroll
        for (int j = 0; j < 2; ++j) {
            const int col = nbase + wn + 32 * j + l31;
            float bv = 0.f;
            if (BIAS) bv = bias[col];
            #pragma unroll
            for (int r = 0; r < 16; ++r) {
                const int row = rowb + (r & 3) + 8 * (r >> 2);
                Cm[(size_t)row * ldc + col] = (bf16)(acc[i][j][r] + bv);
            }
        }
    }
}

// ---------------------------------------------------------------------------
// Kernel 3: windowed attention, one wave per (window, head). 64x64 tiles.
// ---------------------------------------------------------------------------
__global__ __launch_bounds__(64)
void attn_win(const bf16* __restrict__ QKV, bf16* __restrict__ AOut)
{
    const int blk  = blockIdx.x;
    const int bw   = blk / 12;
    const int h    = blk % 12;
    const int lane = threadIdx.x;
    const int quad = lane >> 4;
    const int l16  = lane & 15;

    __shared__ bf16 Kt[64 * 64];
    __shared__ bf16 Vt[64 * 64];

    const size_t rowbase = (size_t)bw * 64;

    {
        const int rsub = lane >> 3;
        const int slot = lane & 7;
        #pragma unroll
        for (int t = 0; t < 8; ++t) {
            const int row = 8 * t + rsub;
            const int kcK = slot ^ (row & 7);
            async16(QKV + (rowbase + row) * 2304 + 768 + h * 64 + kcK * 8,
                    Kt + (8 * t) * 64);
            async16(QKV + (rowbase + row) * 2304 + 1536 + h * 64 + slot * 8,
                    Vt + (8 * t) * 64);
        }
    }

    bf16x8 qf[4][2];
    #pragma unroll
    for (int i = 0; i < 4; ++i)
        #pragma unroll
        for (int ks = 0; ks < 2; ++ks)
            qf[i][ks] = *(const bf16x8*)(QKV + (rowbase + 16 * i + l16) * 2304
                                         + h * 64 + ks * 32 + quad * 8);
    __syncthreads();

    const f32x4 zero = {0.f, 0.f, 0.f, 0.f};
    f32x4 s[4][4];
    #pragma unroll
    for (int i = 0; i < 4; ++i)
        #pragma unroll
        for (int j = 0; j < 4; ++j) s[i][j] = zero;

    #pragma unroll
    for (int ks = 0; ks < 2; ++ks) {
        bf16x8 kf[4];
        #pragma unroll
        for (int j = 0; j < 4; ++j) {
            const int row  = 16 * j + l16;
            const int slot = (ks * 4 + quad) ^ (row & 7);
            kf[j] = *(const bf16x8*)(Kt + row * 64 + slot * 8);
        }
        #pragma unroll
        for (int i = 0; i < 4; ++i)
            #pragma unroll
            for (int j = 0; j < 4; ++j)
                s[i][j] = __builtin_amdgcn_mfma_f32_16x16x32_bf16(
                    qf[i][ks], kf[j], s[i][j], 0, 0, 0);
    }

    float rrec[4][4];
    #pragma unroll
    for (int i = 0; i < 4; ++i) {
        #pragma unroll
        for (int r = 0; r < 4; ++r) {
            float mx = s[i][0][r];
            #pragma unroll
            for (int j = 1; j < 4; ++j) mx = fmaxf(mx, s[i][j][r]);
            #pragma unroll
            for (int d = 1; d < 16; d <<= 1) mx = fmaxf(mx, __shfl_xor(mx, d, 64));
            float sum = 0.f;
            #pragma unroll
            for (int j = 0; j < 4; ++j) {
                float p = __expf((s[i][j][r] - mx) * 0.125f);
                s[i][j][r] = p;
                sum += p;
            }
            #pragma unroll
            for (int d = 1; d < 16; d <<= 1) sum += __shfl_xor(sum, d, 64);
            rrec[i][r] = 1.f / sum;
        }
    }

    #pragma unroll
    for (int i = 0; i < 4; ++i)
        #pragma unroll
        for (int j = 0; j < 4; ++j)
            #pragma unroll
            for (int r = 0; r < 4; ++r) {
                const int row  = 16 * i + quad * 4 + r;
                const int col  = 16 * j + l16;
                const int slot = (col >> 3) ^ (row & 7);
                Kt[row * 64 + slot * 8 + (col & 7)] = (bf16)s[i][j][r];
            }
    __syncthreads();

    f32x4 o[4][4];
    #pragma unroll
    for (int i = 0; i < 4; ++i)
        #pragma unroll
        for (int j = 0; j < 4; ++j) o[i][j] = zero;

    #pragma unroll
    for (int ks = 0; ks < 2; ++ks) {
        bf16x8 pf[4], vf[4];
        #pragma unroll
        for (int i = 0; i < 4; ++i) {
            const int row  = 16 * i + l16;
            const int slot = (ks * 4 + quad) ^ (row & 7);
            pf[i] = *(const bf16x8*)(Kt + row * 64 + slot * 8);
        }
        #pragma unroll
        for (int j = 0; j < 4; ++j) {
            bf16x8 t;
            #pragma unroll
            for (int q = 0; q < 8; ++q)
                t[q] = Vt[(ks * 32 + quad * 8 + q) * 64 + 16 * j + l16];
            vf[j] = t;
        }
        #pragma unroll
        for (int i = 0; i < 4; ++i)
            #pragma unroll
            for (int j = 0; j < 4; ++j)
                o[i][j] = __builtin_amdgcn_mfma_f32_16x16x32_bf16(
                    pf[i], vf[j], o[i][j], 0, 0, 0);
    }

    #pragma unroll
    for (int i = 0; i < 4; ++i)
        #pragma unroll
        for (int j = 0; j < 4; ++j)
            #pragma unroll
            for (int r = 0; r < 4; ++r) {
                const size_t grow = rowbase + 16 * i + quad * 4 + r;
                const int col = h * 64 + 16 * j + l16;
                AOut[grow * 768 + col] = (bf16)(o[i][j][r] * rrec[i][r]);
            }
}

// ---------------------------------------------------------------------------
// Kernel 5: LN2 + fc1 (C->1) + exact gelu + fc2 (1->C). 1 wave per row.
// ---------------------------------------------------------------------------
__global__ __launch_bounds__(256)
void final_fused(const bf16* __restrict__ P, const float* __restrict__ g2,
                 const float* __restrict__ b2, const float* __restrict__ fc1w,
                 const float* __restrict__ fc1b, const float* __restrict__ fc2w,
                 const float* __restrict__ fc2b, float* __restrict__ out)
{
    const int row  = blockIdx.x * 4 + (threadIdx.x >> 6);
    const int lane = threadIdx.x & 63;
    const bf16* pr = P + (size_t)row * 768;
    float v[12];
    float sum = 0.f, ssq = 0.f;
    #pragma unroll
    for (int j = 0; j < 3; ++j) {
        bf16x4 c = *(const bf16x4*)(pr + j * 256 + lane * 4);
        #pragma unroll
        for (int q = 0; q < 4; ++q) {
            float f = (float)c[q];
            v[j * 4 + q] = f; sum += f; ssq += f * f;
        }
    }
    #pragma unroll
    for (int d = 1; d < 64; d <<= 1) {
        sum += __shfl_xor(sum, d, 64);
        ssq += __shfl_xor(ssq, d, 64);
    }
    const float mean = sum * (1.f / 768.f);
    const float rstd = rsqrtf(ssq * (1.f / 768.f) - mean * mean + 1e-5f);
    float part = 0.f;
    #pragma unroll
    for (int j = 0; j < 3; ++j) {
        const int c0 = j * 256 + lane * 4;
        f32x4 gg = *(const f32x4*)(g2 + c0);
        f32x4 bb = *(const f32x4*)(b2 + c0);
        f32x4 f1 = *(const f32x4*)(fc1w + c0);
        #pragma unroll
        for (int q = 0; q < 4; ++q) {
            float ln = (v[j * 4 + q] - mean) * rstd * gg[q] + bb[q];
            part += ln * f1[q];
        }
    }
    #pragma unroll
    for (int d = 1; d < 64; d <<= 1) part += __shfl_xor(part, d, 64);
    const float sv = part + fc1b[0];
    const float ge = 0.5f * sv * (1.f + erff(sv * 0.70710678118654752f));
    float* orow = out + (size_t)row * 768;
    #pragma unroll
    for (int j = 0; j < 3; ++j) {
        const int c0 = j * 256 + lane * 4;
        f32x4 f2  = *(const f32x4*)(fc2w + c0);
        f32x4 b2v = *(const f32x4*)(fc2b + c0);
        f32x4 ov;
        #pragma unroll
        for (int q = 0; q < 4; ++q)
            ov[q] = ge * f2[q] + b2v[q];
        *(f32x4*)(orow + c0) = ov;
    }
}

// ---------------------------------------------------------------------------
extern "C" void kernel_launch(void* const* d_in, const int* in_sizes, int n_in,
                              void* d_out, int out_size, void* d_ws, size_t ws_size,
                              hipStream_t stream)
{
    const float* x     = (const float*)d_in[0];
    const float* n1g   = (const float*)d_in[1];
    const float* n1b   = (const float*)d_in[2];
    const float* n2g   = (const float*)d_in[3];
    const float* n2b   = (const float*)d_in[4];
    const float* qkvw  = (const float*)d_in[5];
    const float* projw = (const float*)d_in[6];
    const float* projb = (const float*)d_in[7];
    const float* fc1w  = (const float*)d_in[8];
    const float* fc1b  = (const float*)d_in[9];
    const float* fc2w  = (const float*)d_in[10];
    const float* fc2b  = (const float*)d_in[11];
    float* out = (float*)d_out;

    const int total = in_sizes[0];          // B * 16384 * 768
    const int rows  = total / 768;          // 65536 token rows
    const int Smod  = total / 3;            // 2^24 for B=4
    const int Bw    = rows / 64;            // windows
    const int C     = 768;

    bf16* qkv     = (bf16*)d_ws;
    bf16* Ybuf    = qkv + (size_t)rows * 2304;
    bf16* qkvw_b  = Ybuf + (size_t)rows * 768;
    bf16* projw_b = qkvw_b + (size_t)3 * C * C;
    bf16* Pbuf    = qkv;
    // Gbuf lives in d_out scratch (33.5MB << out_size; final_fused fully
    // overwrites out afterwards).
    bf16* Gb      = (bf16*)d_out;

    const int nqkvw  = 3 * C * C;
    const int nprojw = C * C;
    f2b<<<(nqkvw / 4 + 255) / 256, 256, 0, stream>>>(qkvw, qkvw_b, nqkvw);
    f2b<<<(nprojw / 4 + 255) / 256, 256, 0, stream>>>(projw, projw_b, nprojw);

    ln1_win<<<rows / 4, 256, 0, stream>>>(x, n1g, n1b, Ybuf);

    gsum<<<(Smod / 8 + 255) / 256, 256, 0, stream>>>(Ybuf, Gb, Smod);

    const int nbm = rows / 256;             // 256 m-tiles
    gemm32<1, false><<<nbm * 9, 512, 0, stream>>>(
        nullptr, Ybuf, Gb, qkvw_b, nullptr, qkv, 768, 2304, Smod, 9);

    attn_win<<<Bw * 12, 64, 0, stream>>>(qkv, Ybuf);

    gemm32<0, true><<<nbm * 3, 512, 0, stream>>>(
        Ybuf, nullptr, nullptr, projw_b, projb, Pbuf, 768, 768, 0, 3);

    final_fused<<<rows / 4, 256, 0, stream>>>(Pbuf, n2g, n2b, fc1w, fc1b,
                                              fc2w, fc2b, out);
}